// Round 3
// baseline (1049.450 us; speedup 1.0000x reference)
//
#include <hip/hip_runtime.h>
#include <stdint.h>

// Problem constants: B=2, S=2048, D=1024, H=16, Dk=64
// I/O dtype: float32 (per reference). Internal compute: bf16 MFMA, f32 accum.
#define SB 2048
#define DM 1024
#define NHH 16
#define DKK 64

typedef unsigned short u16;
using short8  = __attribute__((ext_vector_type(8))) short;
using short4v = __attribute__((ext_vector_type(4))) short;
using f32x4   = __attribute__((ext_vector_type(4))) float;

__device__ __forceinline__ u16 f2bf(float f) {
    union { float f; unsigned u; } v; v.f = f;
    unsigned u = v.u;
    return (u16)((u + 0x7FFFu + ((u >> 16) & 1u)) >> 16);  // RNE
}

// stage 16 consecutive f32 -> 16 bf16 (both 16B-aligned)
__device__ __forceinline__ void stage16(const float* __restrict__ src, u16* dst) {
    const float4* s4 = (const float4*)src;
#pragma unroll
    for (int t = 0; t < 2; ++t) {
        const float4 a = s4[2 * t], b = s4[2 * t + 1];
        short8 p;
        p[0] = (short)f2bf(a.x); p[1] = (short)f2bf(a.y);
        p[2] = (short)f2bf(a.z); p[3] = (short)f2bf(a.w);
        p[4] = (short)f2bf(b.x); p[5] = (short)f2bf(b.y);
        p[6] = (short)f2bf(b.z); p[7] = (short)f2bf(b.w);
        *(short8*)(dst + 8 * t) = p;
    }
}

// ---------------------------------------------------------------------------
// Projection GEMM:  Y[m,n] = sum_k X[m,k]*W[n,k] + bias[n]   (NT, M=4096,N=K=1024)
// X,W,bias f32; Y bf16 scratch.
// vmode 0: Y stored as qh/kh layout (B,H,S,Dk)
// vmode 1: Y stored transposed      (B,H,Dk,S)
// ---------------------------------------------------------------------------
__global__ __launch_bounds__(256) void proj_kernel(
    const float* __restrict__ X, const float* __restrict__ W,
    const float* __restrict__ Bv, u16* __restrict__ Y, int vmode)
{
    __shared__ __align__(16) u16 As[64 * 72];
    __shared__ __align__(16) u16 Bs[64 * 72];

    const int tid  = threadIdx.x;
    const int lane = tid & 63, wv = tid >> 6;
    const int li = lane & 15, g = lane >> 4;
    const int wr = wv >> 1, wc = wv & 1;
    const int m0 = blockIdx.y * 64, n0 = blockIdx.x * 64;

    f32x4 acc[2][2] = {};

    const int rs = tid >> 2;          // 0..63
    const int cs = (tid & 3) * 16;    // 0,16,32,48

    for (int k0 = 0; k0 < DM; k0 += 64) {
        stage16(&X[(m0 + rs) * DM + k0 + cs], &As[rs * 72 + cs]);
        stage16(&W[(n0 + rs) * DM + k0 + cs], &Bs[rs * 72 + cs]);
        __syncthreads();
#pragma unroll
        for (int kk = 0; kk < 2; ++kk) {
            short8 a0 = *(const short8*)&As[(wr * 32 + li) * 72 + kk * 32 + g * 8];
            short8 a1 = *(const short8*)&As[(wr * 32 + 16 + li) * 72 + kk * 32 + g * 8];
            short8 b0 = *(const short8*)&Bs[(wc * 32 + li) * 72 + kk * 32 + g * 8];
            short8 b1 = *(const short8*)&Bs[(wc * 32 + 16 + li) * 72 + kk * 32 + g * 8];
            acc[0][0] = __builtin_amdgcn_mfma_f32_16x16x32_bf16(a0, b0, acc[0][0], 0, 0, 0);
            acc[0][1] = __builtin_amdgcn_mfma_f32_16x16x32_bf16(a0, b1, acc[0][1], 0, 0, 0);
            acc[1][0] = __builtin_amdgcn_mfma_f32_16x16x32_bf16(a1, b0, acc[1][0], 0, 0, 0);
            acc[1][1] = __builtin_amdgcn_mfma_f32_16x16x32_bf16(a1, b1, acc[1][1], 0, 0, 0);
        }
        __syncthreads();
    }

#pragma unroll
    for (int i = 0; i < 2; ++i)
#pragma unroll
        for (int j = 0; j < 2; ++j) {
            const int n = n0 + wc * 32 + j * 16 + li;
            const float bv = Bv[n];
            const int mbase = m0 + wr * 32 + i * 16 + g * 4;
            const int h = n >> 6, dk = n & 63;
            if (vmode == 0) {
#pragma unroll
                for (int r = 0; r < 4; ++r) {
                    const int m = mbase + r;
                    const int b = m >> 11, s = m & 2047;
                    Y[(((b * NHH + h) * SB) + s) * DKK + dk] = f2bf(acc[i][j][r] + bv);
                }
            } else {
                const int b = mbase >> 11, s = mbase & 2047;
                short4v pk;
                pk.x = (short)f2bf(acc[i][j][0] + bv);
                pk.y = (short)f2bf(acc[i][j][1] + bv);
                pk.z = (short)f2bf(acc[i][j][2] + bv);
                pk.w = (short)f2bf(acc[i][j][3] + bv);
                *(short4v*)&Y[(((b * NHH + h) * DKK) + dk) * SB + s] = pk;
            }
        }
}

// ---------------------------------------------------------------------------
// Softmax attention: per workgroup: one (b,h) and 32 q-rows. 4 waves x 512 keys.
// qh/kh bf16 scratch in; normalized P written f32 to attn_out (final output 1).
// ---------------------------------------------------------------------------
__global__ __launch_bounds__(256) void attn_kernel(
    const u16* __restrict__ qh, const u16* __restrict__ kh,
    const int* __restrict__ mask, float* __restrict__ attn_out)
{
    __shared__ __align__(16) float sm[4][32];
    __shared__ __align__(16) float sl[4][32];

    const int tid = threadIdx.x, lane = tid & 63, w = tid >> 6;
    const int li = lane & 15, g = lane >> 4;
    const int bh = blockIdx.y;           // b*16+h
    const int q0 = blockIdx.x * 32;
    const int b  = bh >> 4;
    const float sc2 = 0.125f * 1.44269504088896f;   // (1/sqrt(Dk)) * log2(e)
    const float NEGI = -1.0e30f;

    short8 qa[2][2];
#pragma unroll
    for (int qs = 0; qs < 2; ++qs)
#pragma unroll
        for (int kk = 0; kk < 2; ++kk)
            qa[qs][kk] = *(const short8*)&qh[((bh * SB) + q0 + qs * 16 + li) * DKK + kk * 32 + g * 8];

    float mloc[2][4], lloc[2][4];
#pragma unroll
    for (int qs = 0; qs < 2; ++qs)
#pragma unroll
        for (int r = 0; r < 4; ++r) { mloc[qs][r] = NEGI; lloc[qs][r] = 0.f; }

    const int kbase = w * 512;

    // ---- pass 1: lane-local online max/sum ----
    for (int kt = 0; kt < 32; ++kt) {
        const int key0 = kbase + kt * 16;
        const short8 kb0 = *(const short8*)&kh[((bh * SB) + key0 + li) * DKK + g * 8];
        const short8 kb1 = *(const short8*)&kh[((bh * SB) + key0 + li) * DKK + 32 + g * 8];
        const int mv = mask[b * SB + key0 + li];
#pragma unroll
        for (int qs = 0; qs < 2; ++qs) {
            f32x4 acc = {};
            acc = __builtin_amdgcn_mfma_f32_16x16x32_bf16(qa[qs][0], kb0, acc, 0, 0, 0);
            acc = __builtin_amdgcn_mfma_f32_16x16x32_bf16(qa[qs][1], kb1, acc, 0, 0, 0);
#pragma unroll
            for (int r = 0; r < 4; ++r) {
                const float s2 = (mv == 0) ? -1.442695e9f : acc[r] * sc2;
                const float mo = mloc[qs][r];
                const float mn = fmaxf(mo, s2);
                lloc[qs][r] = lloc[qs][r] * exp2f(mo - mn) + exp2f(s2 - mn);
                mloc[qs][r] = mn;
            }
        }
    }
    // merge across 16 lanes holding the same q-row (masks 1..8 stay in-group)
#pragma unroll
    for (int qs = 0; qs < 2; ++qs)
#pragma unroll
        for (int r = 0; r < 4; ++r) {
            float m = mloc[qs][r], l = lloc[qs][r];
#pragma unroll
            for (int xm = 1; xm < 16; xm <<= 1) {
                const float om = __shfl_xor(m, xm);
                const float ol = __shfl_xor(l, xm);
                const float mn = fmaxf(m, om);
                l = l * exp2f(m - mn) + ol * exp2f(om - mn);
                m = mn;
            }
            mloc[qs][r] = m; lloc[qs][r] = l;
        }
    if (li == 0) {
#pragma unroll
        for (int qs = 0; qs < 2; ++qs)
#pragma unroll
            for (int r = 0; r < 4; ++r) {
                sm[w][qs * 16 + g * 4 + r] = mloc[qs][r];
                sl[w][qs * 16 + g * 4 + r] = lloc[qs][r];
            }
    }
    __syncthreads();

    float M2[2][4], Li[2][4];
#pragma unroll
    for (int qs = 0; qs < 2; ++qs)
#pragma unroll
        for (int r = 0; r < 4; ++r) {
            const int rr = qs * 16 + g * 4 + r;
            const float M = fmaxf(fmaxf(sm[0][rr], sm[1][rr]), fmaxf(sm[2][rr], sm[3][rr]));
            const float L = sl[0][rr] * exp2f(sm[0][rr] - M) + sl[1][rr] * exp2f(sm[1][rr] - M)
                          + sl[2][rr] * exp2f(sm[2][rr] - M) + sl[3][rr] * exp2f(sm[3][rr] - M);
            M2[qs][r] = M;
            Li[qs][r] = 1.0f / L;
        }

    // ---- pass 2: recompute (bitwise-identical), write normalized P (f32) ----
    for (int kt = 0; kt < 32; ++kt) {
        const int key0 = kbase + kt * 16;
        const short8 kb0 = *(const short8*)&kh[((bh * SB) + key0 + li) * DKK + g * 8];
        const short8 kb1 = *(const short8*)&kh[((bh * SB) + key0 + li) * DKK + 32 + g * 8];
        const int mv = mask[b * SB + key0 + li];
#pragma unroll
        for (int qs = 0; qs < 2; ++qs) {
            f32x4 acc = {};
            acc = __builtin_amdgcn_mfma_f32_16x16x32_bf16(qa[qs][0], kb0, acc, 0, 0, 0);
            acc = __builtin_amdgcn_mfma_f32_16x16x32_bf16(qa[qs][1], kb1, acc, 0, 0, 0);
#pragma unroll
            for (int r = 0; r < 4; ++r) {
                const float s2 = (mv == 0) ? -1.442695e9f : acc[r] * sc2;
                const float p = exp2f(s2 - M2[qs][r]) * Li[qs][r];
                const int qrow = q0 + qs * 16 + g * 4 + r;
                attn_out[((size_t)(bh * SB + qrow)) * SB + key0 + li] = p;
            }
        }
    }
}

// ---------------------------------------------------------------------------
// PV GEMM per (b,h):  OH[m,dk] = sum_key P[m,key] * VT[dk,key]
// P f32 (from attn output), VT bf16 scratch; OH bf16 scratch.
// ---------------------------------------------------------------------------
__global__ __launch_bounds__(256) void pv_kernel(
    const float* __restrict__ Pmat, const u16* __restrict__ vt, u16* __restrict__ oh)
{
    __shared__ __align__(16) u16 As[64 * 72];
    __shared__ __align__(16) u16 Bs[64 * 72];

    const int tid  = threadIdx.x;
    const int lane = tid & 63, wv = tid >> 6;
    const int li = lane & 15, g = lane >> 4;
    const int wr = wv >> 1, wc = wv & 1;
    const int bh = blockIdx.y;
    const int m0 = blockIdx.x * 64;
    const size_t pbase = (size_t)bh * SB * SB;

    f32x4 acc[2][2] = {};
    const int rs = tid >> 2;          // 0..63
    const int cs = (tid & 3) * 16;    // 0,16,32,48
    const int r0 = tid >> 3;          // 0..31
    const int c0 = (tid & 7) * 8;     // 0..56

    for (int k0 = 0; k0 < SB; k0 += 64) {
        stage16(&Pmat[pbase + (size_t)(m0 + rs) * SB + k0 + cs], &As[rs * 72 + cs]);
        *(short8*)&Bs[r0 * 72 + c0]        = *(const short8*)&vt[(bh * DKK + r0) * SB + k0 + c0];
        *(short8*)&Bs[(r0 + 32) * 72 + c0] = *(const short8*)&vt[(bh * DKK + r0 + 32) * SB + k0 + c0];
        __syncthreads();
#pragma unroll
        for (int kk = 0; kk < 2; ++kk) {
            short8 a0 = *(const short8*)&As[(wr * 32 + li) * 72 + kk * 32 + g * 8];
            short8 a1 = *(const short8*)&As[(wr * 32 + 16 + li) * 72 + kk * 32 + g * 8];
            short8 b0 = *(const short8*)&Bs[(wc * 32 + li) * 72 + kk * 32 + g * 8];
            short8 b1 = *(const short8*)&Bs[(wc * 32 + 16 + li) * 72 + kk * 32 + g * 8];
            acc[0][0] = __builtin_amdgcn_mfma_f32_16x16x32_bf16(a0, b0, acc[0][0], 0, 0, 0);
            acc[0][1] = __builtin_amdgcn_mfma_f32_16x16x32_bf16(a0, b1, acc[0][1], 0, 0, 0);
            acc[1][0] = __builtin_amdgcn_mfma_f32_16x16x32_bf16(a1, b0, acc[1][0], 0, 0, 0);
            acc[1][1] = __builtin_amdgcn_mfma_f32_16x16x32_bf16(a1, b1, acc[1][1], 0, 0, 0);
        }
        __syncthreads();
    }

#pragma unroll
    for (int i = 0; i < 2; ++i)
#pragma unroll
        for (int j = 0; j < 2; ++j) {
            const int n = wc * 32 + j * 16 + li;                 // dk
            const int mbase = m0 + wr * 32 + i * 16 + g * 4;
#pragma unroll
            for (int r = 0; r < 4; ++r)
                oh[((bh * SB) + mbase + r) * DKK + n] = f2bf(acc[i][j][r]);
        }
}

// ---------------------------------------------------------------------------
// Output projection: out[m,n] = sum_k OH[m,k]*Wo[n,k] + bo[n]
// OH bf16 scratch (B,H,S,Dk) gathered on K; Wo/bo f32; out f32.
// ---------------------------------------------------------------------------
__global__ __launch_bounds__(256) void oproj_kernel(
    const u16* __restrict__ OH, const float* __restrict__ W,
    const float* __restrict__ Bv, float* __restrict__ Y)
{
    __shared__ __align__(16) u16 As[64 * 72];
    __shared__ __align__(16) u16 Bs[64 * 72];

    const int tid  = threadIdx.x;
    const int lane = tid & 63, wv = tid >> 6;
    const int li = lane & 15, g = lane >> 4;
    const int wr = wv >> 1, wc = wv & 1;
    const int m0 = blockIdx.y * 64, n0 = blockIdx.x * 64;

    f32x4 acc[2][2] = {};
    const int rs = tid >> 2;          // 0..63
    const int cs = (tid & 3) * 16;    // 0,16,32,48
    const int r0 = tid >> 3;          // 0..31
    const int c0 = (tid & 7) * 8;     // 0..56

    for (int k0 = 0; k0 < DM; k0 += 64) {
        const int h = k0 >> 6;
        {
            const int m = m0 + r0, bb = m >> 11, s = m & 2047;
            *(short8*)&As[r0 * 72 + c0] =
                *(const short8*)&OH[(((bb * NHH + h) * SB) + s) * DKK + c0];
        }
        {
            const int m = m0 + r0 + 32, bb = m >> 11, s = m & 2047;
            *(short8*)&As[(r0 + 32) * 72 + c0] =
                *(const short8*)&OH[(((bb * NHH + h) * SB) + s) * DKK + c0];
        }
        stage16(&W[(n0 + rs) * DM + k0 + cs], &Bs[rs * 72 + cs]);
        __syncthreads();
#pragma unroll
        for (int kk = 0; kk < 2; ++kk) {
            short8 a0 = *(const short8*)&As[(wr * 32 + li) * 72 + kk * 32 + g * 8];
            short8 a1 = *(const short8*)&As[(wr * 32 + 16 + li) * 72 + kk * 32 + g * 8];
            short8 b0 = *(const short8*)&Bs[(wc * 32 + li) * 72 + kk * 32 + g * 8];
            short8 b1 = *(const short8*)&Bs[(wc * 32 + 16 + li) * 72 + kk * 32 + g * 8];
            acc[0][0] = __builtin_amdgcn_mfma_f32_16x16x32_bf16(a0, b0, acc[0][0], 0, 0, 0);
            acc[0][1] = __builtin_amdgcn_mfma_f32_16x16x32_bf16(a0, b1, acc[0][1], 0, 0, 0);
            acc[1][0] = __builtin_amdgcn_mfma_f32_16x16x32_bf16(a1, b0, acc[1][0], 0, 0, 0);
            acc[1][1] = __builtin_amdgcn_mfma_f32_16x16x32_bf16(a1, b1, acc[1][1], 0, 0, 0);
        }
        __syncthreads();
    }

#pragma unroll
    for (int i = 0; i < 2; ++i)
#pragma unroll
        for (int j = 0; j < 2; ++j) {
            const int n = n0 + wc * 32 + j * 16 + li;
            const float bv = Bv[n];
            const int mbase = m0 + wr * 32 + i * 16 + g * 4;
#pragma unroll
            for (int r = 0; r < 4; ++r)
                Y[(mbase + r) * DM + n] = acc[i][j][r] + bv;
        }
}

// ---------------------------------------------------------------------------
extern "C" void kernel_launch(void* const* d_in, const int* in_sizes, int n_in,
                              void* d_out, int out_size, void* d_ws, size_t ws_size,
                              hipStream_t stream) {
    const float* q    = (const float*)d_in[0];
    const float* k    = (const float*)d_in[1];
    const float* v    = (const float*)d_in[2];
    const int*   mask = (const int*)d_in[3];
    const float* wq   = (const float*)d_in[4];
    const float* bq   = (const float*)d_in[5];
    const float* wk   = (const float*)d_in[6];
    const float* bk   = (const float*)d_in[7];
    const float* wv   = (const float*)d_in[8];
    const float* bv   = (const float*)d_in[9];
    const float* wo   = (const float*)d_in[10];
    const float* bo   = (const float*)d_in[11];

    float* out  = (float*)d_out;             // (B,S,D) = 4,194,304 f32
    float* attn = out + 4194304;             // (B,H,S,S) = 134,217,728 f32

    // bf16 scratch: 24 MB total. qh slot is dead after attn_kernel; reuse for oh.
    u16* ws = (u16*)d_ws;
    u16* qh = ws;                            // (B,H,S,Dk)  [0,8MB)
    u16* kh = ws + 1 * 4194304;              // (B,H,S,Dk)  [8,16MB)
    u16* vt = ws + 2 * 4194304;              // (B,H,Dk,S)  [16,24MB)
    u16* oh = ws;                            // reuses qh slot

    dim3 blk(256);
    proj_kernel<<<dim3(16, 64), blk, 0, stream>>>(q, wq, bq, qh, 0);
    proj_kernel<<<dim3(16, 64), blk, 0, stream>>>(k, wk, bk, kh, 0);
    proj_kernel<<<dim3(16, 64), blk, 0, stream>>>(v, wv, bv, vt, 1);
    attn_kernel<<<dim3(64, 32), blk, 0, stream>>>(qh, kh, mask, attn);
    pv_kernel<<<dim3(32, 32), blk, 0, stream>>>(attn, vt, oh);
    oproj_kernel<<<dim3(16, 64), blk, 0, stream>>>(oh, wo, bo, out);
}